// Round 16
// baseline (330.759 us; speedup 1.0000x reference)
//
#include <hip/hip_runtime.h>
#include <stdint.h>

typedef unsigned short u16;
typedef __bf16 bf16x8 __attribute__((ext_vector_type(8)));
typedef float f32x4 __attribute__((ext_vector_type(4)));

#define SEQ   2048
#define EMBED 4096
#define KDIM  4096
#define NH    32
#define NKV   16
#define HD    128
#define KVW   2048   // N_KV_HEADS * HD

__device__ __forceinline__ float bf2f(u16 u) {
  union { uint32_t u; float f; } v; v.u = ((uint32_t)u) << 16; return v.f;
}
__device__ __forceinline__ u16 f2bf(float f) {
  union { float f; uint32_t u; } v; v.f = f;
  return (u16)((v.u + 0x7FFFu + ((v.u >> 16) & 1u)) >> 16);
}
__device__ __forceinline__ void g2l16(const u16* g, u16* l) {
  __builtin_amdgcn_global_load_lds(
      (const __attribute__((address_space(1))) uint32_t*)g,
      (__attribute__((address_space(3))) uint32_t*)l, 16, 0, 0);
}
#define SB() __builtin_amdgcn_sched_barrier(0)

// ---------------- prep: x f32->bf16 + wq/wk/wv transpose+convert ------------
__global__ __launch_bounds__(256) void prep_kernel(
    const float* __restrict__ X, u16* __restrict__ Xb,
    const float* __restrict__ wq, u16* __restrict__ wqT,
    const float* __restrict__ wk, u16* __restrict__ wkT,
    const float* __restrict__ wv, u16* __restrict__ wvT) {
  __shared__ u16 tile[64][68];
  int b = blockIdx.x;
  const int t = threadIdx.x;
  if (b < 2048) {
    const int nquad = SEQ * EMBED / 4;
    for (int i = b * 256 + t; i < nquad; i += 2048 * 256) {
      float4 v = *(const float4*)(X + (size_t)i * 4);
      ushort4 o;
      o.x = f2bf(v.x); o.y = f2bf(v.y); o.z = f2bf(v.z); o.w = f2bf(v.w);
      *(ushort4*)(Xb + (size_t)i * 4) = o;
    }
    return;
  }
  b -= 2048;
  const float* W; u16* Wt; int N, local;
  if (b < 4096)      { W = wq; Wt = wqT; N = 4096; local = b; }
  else if (b < 6144) { W = wk; Wt = wkT; N = 2048; local = b - 4096; }
  else               { W = wv; Wt = wvT; N = 2048; local = b - 6144; }
  const int nx = N >> 6;
  const int n0 = (local % nx) * 64, k0 = (local / nx) * 64;
#pragma unroll
  for (int i = 0; i < 4; i++) {
    int c = i * 256 + t;
    int r = c >> 4, cq = c & 15;
    float4 v = *(const float4*)(W + (size_t)(k0 + r) * N + n0 + cq * 4);
    tile[r][cq * 4 + 0] = f2bf(v.x); tile[r][cq * 4 + 1] = f2bf(v.y);
    tile[r][cq * 4 + 2] = f2bf(v.z); tile[r][cq * 4 + 3] = f2bf(v.w);
  }
  __syncthreads();
#pragma unroll
  for (int i = 0; i < 4; i++) {
    int c = i * 256 + t;
    int rn = c >> 4, cq = c & 15;
    ushort4 v;
    v.x = tile[cq * 4 + 0][rn];
    v.y = tile[cq * 4 + 1][rn];
    v.z = tile[cq * 4 + 2][rn];
    v.w = tile[cq * 4 + 3][rn];
    *(ushort4*)(Wt + (size_t)(n0 + rn) * KDIM + k0 + cq * 4) = v;
  }
}

// ================= 256x256 GEMM for QKV (counted-lgkm pipeline) ============
__global__ __launch_bounds__(512, 2) void gemm8_qkv(
    const u16* __restrict__ A,
    const u16* __restrict__ B0, const u16* __restrict__ B1,
    const u16* __restrict__ B2,
    u16* __restrict__ Qo, u16* __restrict__ Ko, u16* __restrict__ Vt) {
  __shared__ __align__(16) u16 As[2][256 * 64];
  __shared__ __align__(16) u16 Bs[2][256 * 64];
  const int t = threadIdx.x;
  const int lane = t & 63;
  const int w = t >> 6;
  const int wr = w >> 2;
  const int wc = w & 3;
  const int g = lane >> 4;
  const int l15 = lane & 15;

  const int bid = blockIdx.x;
  const int swz = (bid & 7) * 32 + (bid >> 3);
  const int mb = swz & 7;
  const int nb = swz >> 3;
  const int m0 = mb * 256;

  const u16* Bt; int nrow0;
  if (nb < 16)      { Bt = B0; nrow0 = nb * 256; }
  else if (nb < 24) { Bt = B1; nrow0 = (nb - 16) * 256; }
  else              { Bt = B2; nrow0 = (nb - 24) * 256; }

  auto stageA = [&](int buf, int kt, int h) {
#pragma unroll
    for (int i = 0; i < 2; i++) {
      int c = i * 512 + t;
      int row = c >> 3, sp = c & 7;
      int col = (sp ^ (row & 7)) << 3;
      g2l16(A + (size_t)(m0 + h * 128 + row) * KDIM + kt + col,
            &As[buf][h * 8192 + c * 8]);
    }
  };
  auto stageB = [&](int buf, int kt, int h) {
#pragma unroll
    for (int i = 0; i < 2; i++) {
      int c = i * 512 + t;
      int row = c >> 3, sp = c & 7;
      int col = (sp ^ (row & 7)) << 3;
      g2l16(Bt + (size_t)(nrow0 + h * 128 + row) * KDIM + kt + col,
            &Bs[buf][h * 8192 + c * 8]);
    }
  };

  f32x4 acc[8][4];
#pragma unroll
  for (int i = 0; i < 8; i++)
#pragma unroll
    for (int j = 0; j < 4; j++) acc[i][j] = (f32x4){0.f, 0.f, 0.f, 0.f};

  stageA(0, 0, 0); stageA(0, 0, 1);
  stageB(0, 0, 0); stageB(0, 0, 1);
  stageA(1, 64, 0); stageA(1, 64, 1);
  stageB(1, 64, 0); stageB(1, 64, 1);
  asm volatile("s_waitcnt vmcnt(8)" ::: "memory");
  __builtin_amdgcn_s_barrier();

  const int NT = KDIM / 64;  // 64
  for (int ti = 0; ti < NT; ++ti) {
    const int cur = ti & 1;
    const u16* Asc = As[cur];
    const u16* Bsc = Bs[cur];
    const int ktn2 = (ti + 2) * 64;
    const bool pf = (ti + 2 < NT);
    bf16x8 a0[2][4], a1[2][4], b0[2][2], b1[2][2];

    // ---- phase 0: issue a0,b0 then a1 ; barrier ; lgkmcnt(8) ; MFMA Q00 ----
#pragma unroll
    for (int kk = 0; kk < 2; kk++)
#pragma unroll
      for (int mi = 0; mi < 4; mi++) {
        int r = wr * 128 + mi * 16 + l15;
        int slot = (kk * 4 + g) ^ (r & 7);
        a0[kk][mi] = *(const bf16x8*)(Asc + r * 64 + slot * 8);
      }
#pragma unroll
    for (int kk = 0; kk < 2; kk++)
#pragma unroll
      for (int ni = 0; ni < 2; ni++) {
        int r = wc * 64 + ni * 16 + l15;
        int slot = (kk * 4 + g) ^ (r & 7);
        b0[kk][ni] = *(const bf16x8*)(Bsc + r * 64 + slot * 8);
      }
    SB();   // pin: a0,b0 issued first
#pragma unroll
    for (int kk = 0; kk < 2; kk++)
#pragma unroll
      for (int mi = 0; mi < 4; mi++) {
        int r = wr * 128 + 64 + mi * 16 + l15;
        int slot = (kk * 4 + g) ^ (r & 7);
        a1[kk][mi] = *(const bf16x8*)(Asc + r * 64 + slot * 8);
      }
    SB();   // pin: a1 issued before the barrier
    __builtin_amdgcn_s_barrier();
    asm volatile("s_waitcnt lgkmcnt(8)" ::: "memory");  // a0,b0 done; a1 in flight
    SB();
    __builtin_amdgcn_s_setprio(1);
#pragma unroll
    for (int mi = 0; mi < 4; mi++)
#pragma unroll
      for (int ni = 0; ni < 2; ni++)
#pragma unroll
        for (int kk = 0; kk < 2; kk++)
          acc[mi][ni] = __builtin_amdgcn_mfma_f32_16x16x32_bf16(
              a0[kk][mi], b0[kk][ni], acc[mi][ni], 0, 0, 0);
    __builtin_amdgcn_s_setprio(0);
    __builtin_amdgcn_s_barrier();

    // ---- phase 1: issue b1 ; stage A.h0(t+2) ; lgkmcnt(4) ; MFMA Q10 ----
#pragma unroll
    for (int kk = 0; kk < 2; kk++)
#pragma unroll
      for (int ni = 0; ni < 2; ni++) {
        int r = wc * 64 + (ni + 2) * 16 + l15;
        int slot = (kk * 4 + g) ^ (r & 7);
        b1[kk][ni] = *(const bf16x8*)(Bsc + r * 64 + slot * 8);
      }
    SB();
    if (pf) stageA(cur, ktn2, 0);
    SB();
    __builtin_amdgcn_s_barrier();
    asm volatile("s_waitcnt lgkmcnt(4)" ::: "memory");  // a1 done; b1 in flight
    SB();
    __builtin_amdgcn_s_setprio(1);
#pragma unroll
    for (int mi = 0; mi < 4; mi++)
#pragma unroll
      for (int ni = 0; ni < 2; ni++)
#pragma unroll
        for (int kk = 0; kk < 2; kk++)
          acc[mi + 4][ni] = __builtin_amdgcn_mfma_f32_16x16x32_bf16(
              a1[kk][mi], b0[kk][ni], acc[mi + 4][ni], 0, 0, 0);
    __builtin_amdgcn_s_setprio(0);
    __builtin_amdgcn_s_barrier();

    // ---- phase 2: stage A.h1(t+2) ; lgkmcnt(0) ; MFMA Q11 ----
    if (pf) stageA(cur, ktn2, 1);
    SB();
    __builtin_amdgcn_s_barrier();
    asm volatile("s_waitcnt lgkmcnt(0)" ::: "memory");  // b1 done
    SB();
    __builtin_amdgcn_s_setprio(1);
#pragma unroll
    for (int mi = 0; mi < 4; mi++)
#pragma unroll
      for (int ni = 0; ni < 2; ni++)
#pragma unroll
        for (int kk = 0; kk < 2; kk++)
          acc[mi + 4][ni + 2] = __builtin_amdgcn_mfma_f32_16x16x32_bf16(
              a1[kk][mi], b1[kk][ni], acc[mi + 4][ni + 2], 0, 0, 0);
    __builtin_amdgcn_s_setprio(0);
    __builtin_amdgcn_s_barrier();

    // ---- phase 3: stage B(t+2) ; MFMA Q01 (reg-only) ; vmcnt(8) ----
    if (pf) { stageB(cur, ktn2, 0); stageB(cur, ktn2, 1); }
    SB();
    __builtin_amdgcn_s_barrier();
    __builtin_amdgcn_s_setprio(1);
#pragma unroll
    for (int mi = 0; mi < 4; mi++)
#pragma unroll
      for (int ni = 0; ni < 2; ni++)
#pragma unroll
        for (int kk = 0; kk < 2; kk++)
          acc[mi][ni + 2] = __builtin_amdgcn_mfma_f32_16x16x32_bf16(
              a0[kk][mi], b1[kk][ni], acc[mi][ni + 2], 0, 0, 0);
    __builtin_amdgcn_s_setprio(0);
    if (pf)               asm volatile("s_waitcnt vmcnt(8)" ::: "memory");
    else if (ti + 1 < NT) asm volatile("s_waitcnt vmcnt(0)" ::: "memory");
    __builtin_amdgcn_s_barrier();
  }

#pragma unroll
  for (int mi = 0; mi < 8; mi++) {
#pragma unroll
    for (int ni = 0; ni < 4; ni++) {
      int rowg = m0 + wr * 128 + mi * 16 + g * 4;
      int ncol = nb * 256 + wc * 64 + ni * 16 + l15;
      if (nb < 16) {
#pragma unroll
        for (int r = 0; r < 4; r++)
          Qo[(size_t)(rowg + r) * EMBED + ncol] = f2bf(acc[mi][ni][r]);
      } else if (nb < 24) {
        int nc = ncol - 4096;
#pragma unroll
        for (int r = 0; r < 4; r++)
          Ko[(size_t)(rowg + r) * KVW + nc] = f2bf(acc[mi][ni][r]);
      } else {
        int nc = ncol - 6144;  // kv_head*128 + d
        ushort4 v;
        v.x = f2bf(acc[mi][ni][0]); v.y = f2bf(acc[mi][ni][1]);
        v.z = f2bf(acc[mi][ni][2]); v.w = f2bf(acc[mi][ni][3]);
        *(ushort4*)(Vt + (size_t)nc * SEQ + rowg) = v;
      }
    }
  }
}

// ================= out-proj: BM=128 x BN=256, counted-lgkm, f32 out =========
__global__ __launch_bounds__(512, 2) void gemm8_op(
    const u16* __restrict__ A, const u16* __restrict__ Bt,
    float* __restrict__ Cf) {
  __shared__ __align__(16) u16 As[2][128 * 64];
  __shared__ __align__(16) u16 Bs[2][256 * 64];
  const int t = threadIdx.x;
  const int lane = t & 63;
  const int w = t >> 6;
  const int wr = w >> 2;
  const int wc = w & 3;
  const int g = lane >> 4;
  const int l15 = lane & 15;

  const int bid = blockIdx.x;
  const int swz = (bid & 7) * 32 + (bid >> 3);
  const int mb = swz & 15;
  const int nb = swz >> 4;
  const int m0 = mb * 128;
  const int nrow0 = nb * 256;

  auto stageA = [&](int buf, int kt) {
#pragma unroll
    for (int i = 0; i < 2; i++) {
      int c = i * 512 + t;
      int row = c >> 3, sp = c & 7;
      int col = (sp ^ (row & 7)) << 3;
      g2l16(A + (size_t)(m0 + row) * KDIM + kt + col, &As[buf][c * 8]);
    }
  };
  auto stageB = [&](int buf, int kt) {
#pragma unroll
    for (int i = 0; i < 4; i++) {
      int c = i * 512 + t;
      int row = c >> 3, sp = c & 7;
      int col = (sp ^ (row & 7)) << 3;
      g2l16(Bt + (size_t)(nrow0 + row) * KDIM + kt + col, &Bs[buf][c * 8]);
    }
  };

  f32x4 acc[4][4];
#pragma unroll
  for (int i = 0; i < 4; i++)
#pragma unroll
    for (int j = 0; j < 4; j++) acc[i][j] = (f32x4){0.f, 0.f, 0.f, 0.f};

  stageA(0, 0); stageB(0, 0);
  stageA(1, 64); stageB(1, 64);
  asm volatile("s_waitcnt vmcnt(6)" ::: "memory");
  __builtin_amdgcn_s_barrier();

  const int NT = KDIM / 64;
  for (int ti = 0; ti < NT; ++ti) {
    const int cur = ti & 1;
    const u16* Asc = As[cur];
    const u16* Bsc = Bs[cur];
    const int ktn2 = (ti + 2) * 64;
    bf16x8 a[2][4], b0[2][2], b1[2][2];

    // phase 0: issue a,b0 then b1 ; barrier ; lgkmcnt(4) ; MFMA ni0-1
#pragma unroll
    for (int kk = 0; kk < 2; kk++)
#pragma unroll
      for (int mi = 0; mi < 4; mi++) {
        int r = wr * 64 + mi * 16 + l15;
        int slot = (kk * 4 + g) ^ (r & 7);
        a[kk][mi] = *(const bf16x8*)(Asc + r * 64 + slot * 8);
      }
#pragma unroll
    for (int kk = 0; kk < 2; kk++)
#pragma unroll
      for (int ni = 0; ni < 2; ni++) {
        int r = wc * 64 + ni * 16 + l15;
        int slot = (kk * 4 + g) ^ (r & 7);
        b0[kk][ni] = *(const bf16x8*)(Bsc + r * 64 + slot * 8);
      }
    SB();
#pragma unroll
    for (int kk = 0; kk < 2; kk++)
#pragma unroll
      for (int ni = 0; ni < 2; ni++) {
        int r = wc * 64 + (ni + 2) * 16 + l15;
        int slot = (kk * 4 + g) ^ (r & 7);
        b1[kk][ni] = *(const bf16x8*)(Bsc + r * 64 + slot * 8);
      }
    SB();
    __builtin_amdgcn_s_barrier();
    asm volatile("s_waitcnt lgkmcnt(4)" ::: "memory");  // a,b0 done; b1 in flight
    SB();
    __builtin_amdgcn_s_setprio(1);
#pragma unroll
    for (int mi = 0; mi < 4; mi++)
#pragma unroll
      for (int ni = 0; ni < 2; ni++)
#pragma unroll
        for (int kk = 0; kk < 2; kk++)
          acc[mi][ni] = __builtin_amdgcn_mfma_f32_16x16x32_bf16(
              a[kk][mi], b0[kk][ni], acc[mi][ni], 0, 0, 0);
    __builtin_amdgcn_s_setprio(0);
    __builtin_amdgcn_s_barrier();

    // phase 1: stage t+2 ; lgkmcnt(0) ; MFMA ni2-3 ; vmcnt(6)
    if (ti + 2 < NT) { stageA(cur, ktn2); stageB(cur, ktn2); }
    SB();
    __builtin_amdgcn_s_barrier();
    asm volatile("s_waitcnt lgkmcnt(0)" ::: "memory");
    SB();
    __builtin_amdgcn_s_setprio(1);
#pragma unroll
    for (int mi = 0; mi < 4; mi++)
#pragma unroll
      for (int ni = 0; ni < 2; ni++)
#pragma unroll
        for (int kk = 0; kk < 2; kk++)
          acc[mi][ni + 2] = __builtin_amdgcn_mfma_f32_16x16x32_bf16(
              a[kk][mi], b1[kk][ni], acc[mi][ni + 2], 0, 0, 0);
    __builtin_amdgcn_s_setprio(0);
    if (ti + 2 < NT)      asm volatile("s_waitcnt vmcnt(6)" ::: "memory");
    else if (ti + 1 < NT) asm volatile("s_waitcnt vmcnt(0)" ::: "memory");
    __builtin_amdgcn_s_barrier();
  }

#pragma unroll
  for (int mi = 0; mi < 4; mi++)
#pragma unroll
    for (int ni = 0; ni < 4; ni++) {
      int rowg = m0 + wr * 64 + mi * 16 + g * 4;
      int ncol = nb * 256 + wc * 64 + ni * 16 + l15;
#pragma unroll
      for (int r = 0; r < 4; r++)
        Cf[(size_t)(rowg + r) * 4096 + ncol] = acc[mi][ni][r];
    }
}

// ---------------- RoPE (in place) on K [2048][2048] only ----------------
__global__ __launch_bounds__(256) void rope_k_kernel(
    u16* __restrict__ Kb, const float* __restrict__ freqs,
    const int* __restrict__ start_pos) {
  const int sp = start_pos[0];
  const int total = SEQ * KVW / 2;  // pairs
  for (int idx = blockIdx.x * 256 + threadIdx.x; idx < total;
       idx += gridDim.x * 256) {
    int row = idx >> 10, pi = idx & 1023;
    u16* buf = Kb + (size_t)row * KVW;
    int i = pi & 63;
    float2 cs = *(const float2*)(freqs + (size_t)(sp + row) * 128 + i * 2);
    ushort2 tv = *(ushort2*)(buf + pi * 2);
    float t0 = bf2f(tv.x), t1 = bf2f(tv.y);
    ushort2 o;
    o.x = f2bf(t0 * cs.x - t1 * cs.y);
    o.y = f2bf(t0 * cs.y + t1 * cs.x);
    *(ushort2*)(buf + pi * 2) = o;
  }
}

// ---------------- flash attention + wo-transpose backfill -------------------
__global__ __launch_bounds__(256, 4) void attn_kernel(
    const u16* __restrict__ Q, const u16* __restrict__ Kb,
    const u16* __restrict__ Vt, u16* __restrict__ O,
    const float* __restrict__ freqs, const int* __restrict__ start_pos,
    const float* __restrict__ wo, u16* __restrict__ woT) {
  __shared__ __align__(16) u16 KV[16384];   // K: [0,8192) 64x128, V: [8192,..) 128x64
  __shared__ u16 Ps[4][16 * 72];

  const int t = threadIdx.x;
  const int bid = blockIdx.x;

  if (bid >= 1024) {  // ---- wo transpose tile ----
    u16 (*tile)[68] = (u16(*)[68])KV;
    const int local = bid - 1024;       // 0..4095
    const int n0 = (local & 63) * 64, k0 = (local >> 6) * 64;
#pragma unroll
    for (int i = 0; i < 4; i++) {
      int c = i * 256 + t;
      int r = c >> 4, cq = c & 15;
      float4 v = *(const float4*)(wo + (size_t)(k0 + r) * 4096 + n0 + cq * 4);
      tile[r][cq * 4 + 0] = f2bf(v.x); tile[r][cq * 4 + 1] = f2bf(v.y);
      tile[r][cq * 4 + 2] = f2bf(v.z); tile[r][cq * 4 + 3] = f2bf(v.w);
    }
    __syncthreads();
#pragma unroll
    for (int i = 0; i < 4; i++) {
      int c = i * 256 + t;
      int rn = c >> 4, cq = c & 15;
      ushort4 v;
      v.x = tile[cq * 4 + 0][rn];
      v.y = tile[cq * 4 + 1][rn];
      v.z = tile[cq * 4 + 2][rn];
      v.w = tile[cq * 4 + 3][rn];
      *(ushort4*)(woT + (size_t)(n0 + rn) * KDIM + k0 + cq * 4) = v;
    }
    return;
  }

  const int lane = t & 63;
  const int w = t >> 6;
  const int g = lane >> 4;
  const int l15 = lane & 15;
  const int qb = 31 - (bid >> 5);
  const int h = bid & 31;
  const int hk = h >> 1;

  auto stageK = [&](int kv) {
#pragma unroll
    for (int i = 0; i < 4; i++) {
      int c = i * 256 + t;
      int row = c >> 4, spp = c & 15;
      int col = ((spp ^ (row & 7)) << 3);
      g2l16(Kb + (size_t)(kv * 64 + row) * KVW + hk * HD + col, &KV[c * 8]);
    }
  };
  auto stageV = [&](int kv) {
#pragma unroll
    for (int i = 0; i < 4; i++) {
      int c = i * 256 + t;
      int row = c >> 3, spp = c & 7;
      int col = ((spp ^ (row & 7)) << 3);
      g2l16(Vt + (size_t)(hk * HD + row) * SEQ + kv * 64 + col,
            &KV[8192 + c * 8]);
    }
  };

#pragma unroll
  for (int i = 0; i < 4; i++) {
    int c = i * 256 + t;
    int row = c >> 4, spp = c & 15;
    int col = ((spp ^ (row & 7)) << 3);
    g2l16(Q + (size_t)(qb * 64 + row) * EMBED + h * HD + col, &KV[c * 8]);
  }
  asm volatile("s_waitcnt vmcnt(0)" ::: "memory");
  __builtin_amdgcn_s_barrier();

  // read Q fragments + apply RoPE in-register
  bf16x8 qf[4];
  {
    const int r = w * 16 + l15;
    const int frow = start_pos[0] + qb * 64 + r;
    const float qscale = 0.08838834764831845f;  // 1/sqrt(128)
#pragma unroll
    for (int kk = 0; kk < 4; kk++) {
      int ps = (kk * 4 + g) ^ (r & 7);
      bf16x8 v = *(const bf16x8*)(&KV[r * 128 + ps * 8]);
      bf16x8 o;
      const int d0 = (kk * 4 + g) * 8;   // actual d-octet (swizzle cancels)
#pragma unroll
      for (int p = 0; p < 4; p++) {
        float2 cs = *(const float2*)(freqs + (size_t)frow * 128 + d0 + p * 2);
        float t0 = (float)v[2 * p], t1 = (float)v[2 * p + 1];
        o[2 * p]     = (__bf16)((t0 * cs.x - t1 * cs.y) * qscale);
        o[2 * p + 1] = (__bf16)((t0 * cs.y + t1 * cs.x) * qscale);
      }
      qf[kk] = o;
    }
  }
  asm volatile("s_waitcnt lgkmcnt(0)" ::: "memory");
  __builtin_amdgcn_s_barrier();

  f32x4 oacc[8];
#pragma unroll
  for (int i = 0; i < 8; i++) oacc[i] = (f32x4){0.f, 0.f, 0.f, 0.f};
  float mrow = -1e30f, lrow = 0.f;
  const int qg = qb * 64 + w * 16 + l15;

  for (int kv = 0; kv <= qb; kv++) {
    stageK(kv); stageV(kv);
    asm volatile("s_waitcnt vmcnt(0)" ::: "memory");
    __builtin_amdgcn_s_barrier();

    f32x4 sfragT[4];
    __builtin_amdgcn_s_setprio(1);
#pragma unroll
    for (int ni = 0; ni < 4; ni++) {
      f32x4 s = (f32x4){0.f, 0.f, 0.f, 0.f};
      int r = ni * 16 + l15;
#pragma unroll
      for (int kk = 0; kk < 4; kk++) {
        int ps = (kk * 4 + g) ^ (r & 7);
        bf16x8 a = *(const bf16x8*)(&KV[r * 128 + ps * 8]);
        s = __builtin_amdgcn_mfma_f32_16x16x32_bf16(a, qf[kk], s, 0, 0, 0);
      }
      sfragT[ni] = s;
    }
    __builtin_amdgcn_s_setprio(0);

    if (kv == qb) {
#pragma unroll
      for (int ni = 0; ni < 4; ni++) {
        int colg = kv * 64 + ni * 16 + g * 4;
#pragma unroll
        for (int r = 0; r < 4; r++)
          if (colg + r > qg) sfragT[ni][r] = -1e30f;
      }
    }

    float m16 = sfragT[0][0];
#pragma unroll
    for (int ni = 0; ni < 4; ni++)
#pragma unroll
      for (int r = 0; r < 4; r++) m16 = fmaxf(m16, sfragT[ni][r]);
    m16 = fmaxf(m16, __shfl_xor(m16, 16));
    m16 = fmaxf(m16, __shfl_xor(m16, 32));
    float mnew = fmaxf(mrow, m16);
    float sc = __expf(mrow - mnew);
    mrow = mnew;

    float rsum = 0.f;
#pragma unroll
    for (int ni = 0; ni < 4; ni++) {
#pragma unroll
      for (int r = 0; r < 4; r++) {
        float p = __expf(sfragT[ni][r] - mrow);
        rsum += p;
        Ps[w][l15 * 72 + ni * 16 + g * 4 + r] = f2bf(p);
      }
    }
    rsum += __shfl_xor(rsum, 16);
    rsum += __shfl_xor(rsum, 32);
    lrow = lrow * sc + rsum;

    float scr[4];
#pragma unroll
    for (int r = 0; r < 4; r++) scr[r] = __shfl(sc, g * 4 + r, 64);
#pragma unroll
    for (int nf = 0; nf < 8; nf++)
#pragma unroll
      for (int r = 0; r < 4; r++) oacc[nf][r] *= scr[r];

    asm volatile("s_waitcnt lgkmcnt(0)" ::: "memory");

    bf16x8 pa[2];
#pragma unroll
    for (int kk = 0; kk < 2; kk++)
      pa[kk] = *(const bf16x8*)(&Ps[w][l15 * 72 + kk * 32 + g * 8]);
    __builtin_amdgcn_s_setprio(1);
#pragma unroll
    for (int nf = 0; nf < 8; nf++) {
      int r = nf * 16 + l15;
#pragma unroll
      for (int kk = 0; kk < 2; kk++) {
        int ps = (kk * 4 + g) ^ (r & 7);
        bf16x8 b = *(const bf16x8*)(&KV[8192 + r * 64 + ps * 8]);
        oacc[nf] = __builtin_amdgcn_mfma_f32_16x16x32_bf16(pa[kk], b, oacc[nf], 0, 0, 0);
      }
    }
    __builtin_amdgcn_s_setprio(0);
    __builtin_amdgcn_s_barrier();
  }

  float lr[4];
#pragma unroll
  for (int r = 0; r < 4; r++) lr[r] = __shfl(lrow, g * 4 + r, 64);
#pragma unroll
  for (int nf = 0; nf < 8; nf++) {
#pragma unroll
    for (int r = 0; r < 4; r++) {
      int rowg = qb * 64 + w * 16 + g * 4 + r;
      float v = oacc[nf][r] / lr[r];
      O[(size_t)rowg * EMBED + h * HD + nf * 16 + l15] = f2bf(v);
    }
  }
}

extern "C" void kernel_launch(void* const* d_in, const int* in_sizes, int n_in,
                              void* d_out, int out_size, void* d_ws, size_t ws_size,
                              hipStream_t stream) {
  const float* x  = (const float*)d_in[0];
  const float* fc = (const float*)d_in[1];
  const float* wq = (const float*)d_in[2];
  const float* wk = (const float*)d_in[3];
  const float* wv = (const float*)d_in[4];
  const float* wo = (const float*)d_in[5];
  const int* sp = (const int*)d_in[6];

  char* ws = (char*)d_ws;
  u16* wqT = (u16*)(ws);                      // bf16 [4096][4096]
  u16* wkT = (u16*)(ws + 33554432ull);        // bf16 [2048][4096]
  u16* wvT = (u16*)(ws + 50331648ull);        // bf16 [2048][4096]
  u16* woT = (u16*)(ws + 67108864ull);        // bf16 [4096][4096]
  u16* xb  = (u16*)(ws + 100663296ull);       // bf16 [2048][4096]
  u16* Qb  = (u16*)(ws + 117440512ull);       // bf16 [2048][4096] (raw, no rope)
  u16* Kb  = (u16*)(ws + 134217728ull);       // bf16 [2048][2048]
  u16* Vt  = (u16*)(ws + 142606336ull);       // bf16 [2048][2048]
  u16* Ob  = (u16*)(ws + 150994944ull);       // bf16 [2048][4096]

  prep_kernel<<<dim3(10240), 256, 0, stream>>>(x, xb, wq, wqT, wk, wkT,
                                               wv, wvT);
  gemm8_qkv<<<dim3(256), 512, 0, stream>>>(xb, wqT, wkT, wvT, Qb, Kb, Vt);
  rope_k_kernel<<<dim3(1024), 256, 0, stream>>>(Kb, fc, sp);
  attn_kernel<<<dim3(5120), 256, 0, stream>>>(Qb, Kb, Vt, Ob, fc, sp,
                                              wo, woT);
  gemm8_op<<<dim3(256), 512, 0, stream>>>(Ob, woT, (float*)d_out);
}

// Round 17
// 325.948 us; speedup vs baseline: 1.0148x; 1.0148x over previous
//
#include <hip/hip_runtime.h>
#include <stdint.h>

typedef unsigned short u16;
typedef __bf16 bf16x8 __attribute__((ext_vector_type(8)));
typedef float f32x4 __attribute__((ext_vector_type(4)));

#define SEQ   2048
#define EMBED 4096
#define KDIM  4096
#define NH    32
#define NKV   16
#define HD    128
#define KVW   2048   // N_KV_HEADS * HD

__device__ __forceinline__ float bf2f(u16 u) {
  union { uint32_t u; float f; } v; v.u = ((uint32_t)u) << 16; return v.f;
}
__device__ __forceinline__ u16 f2bf(float f) {
  union { float f; uint32_t u; } v; v.f = f;
  return (u16)((v.u + 0x7FFFu + ((v.u >> 16) & 1u)) >> 16);
}
__device__ __forceinline__ void g2l16(const u16* g, u16* l) {
  __builtin_amdgcn_global_load_lds(
      (const __attribute__((address_space(1))) uint32_t*)g,
      (__attribute__((address_space(3))) uint32_t*)l, 16, 0, 0);
}

// ---------------- prep: x f32->bf16 + wq/wk/wv transpose+convert ------------
__global__ __launch_bounds__(256) void prep_kernel(
    const float* __restrict__ X, u16* __restrict__ Xb,
    const float* __restrict__ wq, u16* __restrict__ wqT,
    const float* __restrict__ wk, u16* __restrict__ wkT,
    const float* __restrict__ wv, u16* __restrict__ wvT) {
  __shared__ u16 tile[64][68];
  int b = blockIdx.x;
  const int t = threadIdx.x;
  if (b < 2048) {
    const int nquad = SEQ * EMBED / 4;
    for (int i = b * 256 + t; i < nquad; i += 2048 * 256) {
      float4 v = *(const float4*)(X + (size_t)i * 4);
      ushort4 o;
      o.x = f2bf(v.x); o.y = f2bf(v.y); o.z = f2bf(v.z); o.w = f2bf(v.w);
      *(ushort4*)(Xb + (size_t)i * 4) = o;
    }
    return;
  }
  b -= 2048;
  const float* W; u16* Wt; int N, local;
  if (b < 4096)      { W = wq; Wt = wqT; N = 4096; local = b; }
  else if (b < 6144) { W = wk; Wt = wkT; N = 2048; local = b - 4096; }
  else               { W = wv; Wt = wvT; N = 2048; local = b - 6144; }
  const int nx = N >> 6;
  const int n0 = (local % nx) * 64, k0 = (local / nx) * 64;
#pragma unroll
  for (int i = 0; i < 4; i++) {
    int c = i * 256 + t;
    int r = c >> 4, cq = c & 15;
    float4 v = *(const float4*)(W + (size_t)(k0 + r) * N + n0 + cq * 4);
    tile[r][cq * 4 + 0] = f2bf(v.x); tile[r][cq * 4 + 1] = f2bf(v.y);
    tile[r][cq * 4 + 2] = f2bf(v.z); tile[r][cq * 4 + 3] = f2bf(v.w);
  }
  __syncthreads();
#pragma unroll
  for (int i = 0; i < 4; i++) {
    int c = i * 256 + t;
    int rn = c >> 4, cq = c & 15;
    ushort4 v;
    v.x = tile[cq * 4 + 0][rn];
    v.y = tile[cq * 4 + 1][rn];
    v.z = tile[cq * 4 + 2][rn];
    v.w = tile[cq * 4 + 3][rn];
    *(ushort4*)(Wt + (size_t)(n0 + rn) * KDIM + k0 + cq * 4) = v;
  }
}

// ================= 256x256 GEMM for QKV (r6 schedule + staggered staging) ===
// Staging spread: A.h0(t+2) in P1, A.h1 in P2, B.h0+h1 in P3 — each region
// staged immediately after its readers drained (lgkmcnt(0)+barrier).
__global__ __launch_bounds__(512, 2) void gemm8_qkv(
    const u16* __restrict__ A,
    const u16* __restrict__ B0, const u16* __restrict__ B1,
    const u16* __restrict__ B2,
    u16* __restrict__ Qo, u16* __restrict__ Ko, u16* __restrict__ Vt) {
  __shared__ __align__(16) u16 As[2][256 * 64];
  __shared__ __align__(16) u16 Bs[2][256 * 64];
  const int t = threadIdx.x;
  const int lane = t & 63;
  const int w = t >> 6;
  const int wr = w >> 2;
  const int wc = w & 3;
  const int g = lane >> 4;
  const int l15 = lane & 15;

  const int bid = blockIdx.x;
  const int swz = (bid & 7) * 32 + (bid >> 3);
  const int mb = swz & 7;
  const int nb = swz >> 3;
  const int m0 = mb * 256;

  const u16* Bt; int nrow0;
  if (nb < 16)      { Bt = B0; nrow0 = nb * 256; }
  else if (nb < 24) { Bt = B1; nrow0 = (nb - 16) * 256; }
  else              { Bt = B2; nrow0 = (nb - 24) * 256; }

  auto stageA = [&](int buf, int kt, int h) {
#pragma unroll
    for (int i = 0; i < 2; i++) {
      int c = i * 512 + t;
      int row = c >> 3, sp = c & 7;
      int col = (sp ^ (row & 7)) << 3;
      g2l16(A + (size_t)(m0 + h * 128 + row) * KDIM + kt + col,
            &As[buf][h * 8192 + c * 8]);
    }
  };
  auto stageB = [&](int buf, int kt, int h) {
#pragma unroll
    for (int i = 0; i < 2; i++) {
      int c = i * 512 + t;
      int row = c >> 3, sp = c & 7;
      int col = (sp ^ (row & 7)) << 3;
      g2l16(Bt + (size_t)(nrow0 + h * 128 + row) * KDIM + kt + col,
            &Bs[buf][h * 8192 + c * 8]);
    }
  };

  f32x4 acc[8][4];
#pragma unroll
  for (int i = 0; i < 8; i++)
#pragma unroll
    for (int j = 0; j < 4; j++) acc[i][j] = (f32x4){0.f, 0.f, 0.f, 0.f};

  stageA(0, 0, 0); stageA(0, 0, 1);
  stageB(0, 0, 0); stageB(0, 0, 1);
  stageA(1, 64, 0); stageA(1, 64, 1);
  stageB(1, 64, 0); stageB(1, 64, 1);
  asm volatile("s_waitcnt vmcnt(8)" ::: "memory");
  __builtin_amdgcn_s_barrier();

  const int NT = KDIM / 64;  // 64
  for (int ti = 0; ti < NT; ++ti) {
    const int cur = ti & 1;
    const u16* Asc = As[cur];
    const u16* Bsc = Bs[cur];
    const int ktn2 = (ti + 2) * 64;
    const bool pf = (ti + 2 < NT);
    bf16x8 a0[2][4], a1[2][4], b0[2][2], b1[2][2];

    // ---- phase 0: read a0+b0 ; MFMA Q00 ----
#pragma unroll
    for (int kk = 0; kk < 2; kk++)
#pragma unroll
      for (int mi = 0; mi < 4; mi++) {
        int r = wr * 128 + mi * 16 + l15;
        int slot = (kk * 4 + g) ^ (r & 7);
        a0[kk][mi] = *(const bf16x8*)(Asc + r * 64 + slot * 8);
      }
#pragma unroll
    for (int kk = 0; kk < 2; kk++)
#pragma unroll
      for (int ni = 0; ni < 2; ni++) {
        int r = wc * 64 + ni * 16 + l15;
        int slot = (kk * 4 + g) ^ (r & 7);
        b0[kk][ni] = *(const bf16x8*)(Bsc + r * 64 + slot * 8);
      }
    __builtin_amdgcn_s_barrier();
    asm volatile("s_waitcnt lgkmcnt(0)" ::: "memory");
    __builtin_amdgcn_sched_barrier(0);
    __builtin_amdgcn_s_setprio(1);
#pragma unroll
    for (int mi = 0; mi < 4; mi++)
#pragma unroll
      for (int ni = 0; ni < 2; ni++)
#pragma unroll
        for (int kk = 0; kk < 2; kk++)
          acc[mi][ni] = __builtin_amdgcn_mfma_f32_16x16x32_bf16(
              a0[kk][mi], b0[kk][ni], acc[mi][ni], 0, 0, 0);
    __builtin_amdgcn_s_setprio(0);
    __builtin_amdgcn_s_barrier();

    // ---- phase 1: read a1 ; stage A.h0(t+2) (a0 region free) ; MFMA Q10 ----
#pragma unroll
    for (int kk = 0; kk < 2; kk++)
#pragma unroll
      for (int mi = 0; mi < 4; mi++) {
        int r = wr * 128 + 64 + mi * 16 + l15;
        int slot = (kk * 4 + g) ^ (r & 7);
        a1[kk][mi] = *(const bf16x8*)(Asc + r * 64 + slot * 8);
      }
    if (pf) stageA(cur, ktn2, 0);
    __builtin_amdgcn_s_barrier();
    asm volatile("s_waitcnt lgkmcnt(0)" ::: "memory");
    __builtin_amdgcn_sched_barrier(0);
    __builtin_amdgcn_s_setprio(1);
#pragma unroll
    for (int mi = 0; mi < 4; mi++)
#pragma unroll
      for (int ni = 0; ni < 2; ni++)
#pragma unroll
        for (int kk = 0; kk < 2; kk++)
          acc[mi + 4][ni] = __builtin_amdgcn_mfma_f32_16x16x32_bf16(
              a1[kk][mi], b0[kk][ni], acc[mi + 4][ni], 0, 0, 0);
    __builtin_amdgcn_s_setprio(0);
    __builtin_amdgcn_s_barrier();

    // ---- phase 2: read b1 ; stage A.h1(t+2) (a1 region free) ; MFMA Q11 ----
#pragma unroll
    for (int kk = 0; kk < 2; kk++)
#pragma unroll
      for (int ni = 0; ni < 2; ni++) {
        int r = wc * 64 + (ni + 2) * 16 + l15;
        int slot = (kk * 4 + g) ^ (r & 7);
        b1[kk][ni] = *(const bf16x8*)(Bsc + r * 64 + slot * 8);
      }
    if (pf) stageA(cur, ktn2, 1);
    __builtin_amdgcn_s_barrier();
    asm volatile("s_waitcnt lgkmcnt(0)" ::: "memory");
    __builtin_amdgcn_sched_barrier(0);
    __builtin_amdgcn_s_setprio(1);
#pragma unroll
    for (int mi = 0; mi < 4; mi++)
#pragma unroll
      for (int ni = 0; ni < 2; ni++)
#pragma unroll
        for (int kk = 0; kk < 2; kk++)
          acc[mi + 4][ni + 2] = __builtin_amdgcn_mfma_f32_16x16x32_bf16(
              a1[kk][mi], b1[kk][ni], acc[mi + 4][ni + 2], 0, 0, 0);
    __builtin_amdgcn_s_setprio(0);
    __builtin_amdgcn_s_barrier();

    // ---- phase 3: stage B.h0+h1(t+2) (b0,b1 free) ; MFMA Q01 ; vmcnt(8) ----
    if (pf) { stageB(cur, ktn2, 0); stageB(cur, ktn2, 1); }
    __builtin_amdgcn_s_barrier();
    __builtin_amdgcn_s_setprio(1);
#pragma unroll
    for (int mi = 0; mi < 4; mi++)
#pragma unroll
      for (int ni = 0; ni < 2; ni++)
#pragma unroll
        for (int kk = 0; kk < 2; kk++)
          acc[mi][ni + 2] = __builtin_amdgcn_mfma_f32_16x16x32_bf16(
              a0[kk][mi], b1[kk][ni], acc[mi][ni + 2], 0, 0, 0);
    __builtin_amdgcn_s_setprio(0);
    if (pf)                    asm volatile("s_waitcnt vmcnt(8)" ::: "memory");
    else if (ti + 1 < NT)      asm volatile("s_waitcnt vmcnt(0)" ::: "memory");
    __builtin_amdgcn_s_barrier();
  }

#pragma unroll
  for (int mi = 0; mi < 8; mi++) {
#pragma unroll
    for (int ni = 0; ni < 4; ni++) {
      int rowg = m0 + wr * 128 + mi * 16 + g * 4;
      int ncol = nb * 256 + wc * 64 + ni * 16 + l15;
      if (nb < 16) {
#pragma unroll
        for (int r = 0; r < 4; r++)
          Qo[(size_t)(rowg + r) * EMBED + ncol] = f2bf(acc[mi][ni][r]);
      } else if (nb < 24) {
        int nc = ncol - 4096;
#pragma unroll
        for (int r = 0; r < 4; r++)
          Ko[(size_t)(rowg + r) * KVW + nc] = f2bf(acc[mi][ni][r]);
      } else {
        int nc = ncol - 6144;  // kv_head*128 + d
        ushort4 v;
        v.x = f2bf(acc[mi][ni][0]); v.y = f2bf(acc[mi][ni][1]);
        v.z = f2bf(acc[mi][ni][2]); v.w = f2bf(acc[mi][ni][3]);
        *(ushort4*)(Vt + (size_t)nc * SEQ + rowg) = v;
      }
    }
  }
}

// ================= out-proj: BM=128 x BN=256, 2-phase/K-tile, f32 out ======
__global__ __launch_bounds__(512, 2) void gemm8_op(
    const u16* __restrict__ A, const u16* __restrict__ Bt,
    float* __restrict__ Cf) {
  __shared__ __align__(16) u16 As[2][128 * 64];
  __shared__ __align__(16) u16 Bs[2][256 * 64];
  const int t = threadIdx.x;
  const int lane = t & 63;
  const int w = t >> 6;
  const int wr = w >> 2;
  const int wc = w & 3;
  const int g = lane >> 4;
  const int l15 = lane & 15;

  const int bid = blockIdx.x;
  const int swz = (bid & 7) * 32 + (bid >> 3);
  const int mb = swz & 15;
  const int nb = swz >> 4;
  const int m0 = mb * 128;
  const int nrow0 = nb * 256;

  auto stageA = [&](int buf, int kt) {
#pragma unroll
    for (int i = 0; i < 2; i++) {
      int c = i * 512 + t;
      int row = c >> 3, sp = c & 7;
      int col = (sp ^ (row & 7)) << 3;
      g2l16(A + (size_t)(m0 + row) * KDIM + kt + col, &As[buf][c * 8]);
    }
  };
  auto stageB = [&](int buf, int kt) {
#pragma unroll
    for (int i = 0; i < 4; i++) {
      int c = i * 512 + t;
      int row = c >> 3, sp = c & 7;
      int col = (sp ^ (row & 7)) << 3;
      g2l16(Bt + (size_t)(nrow0 + row) * KDIM + kt + col, &Bs[buf][c * 8]);
    }
  };

  f32x4 acc[4][4];
#pragma unroll
  for (int i = 0; i < 4; i++)
#pragma unroll
    for (int j = 0; j < 4; j++) acc[i][j] = (f32x4){0.f, 0.f, 0.f, 0.f};

  stageA(0, 0); stageB(0, 0);
  stageA(1, 64); stageB(1, 64);
  asm volatile("s_waitcnt vmcnt(6)" ::: "memory");
  __builtin_amdgcn_s_barrier();

  const int NT = KDIM / 64;
  for (int ti = 0; ti < NT; ++ti) {
    const int cur = ti & 1;
    const u16* Asc = As[cur];
    const u16* Bsc = Bs[cur];
    const int ktn2 = (ti + 2) * 64;
    bf16x8 a[2][4], b0[2][2], b1[2][2];

#pragma unroll
    for (int kk = 0; kk < 2; kk++)
#pragma unroll
      for (int mi = 0; mi < 4; mi++) {
        int r = wr * 64 + mi * 16 + l15;
        int slot = (kk * 4 + g) ^ (r & 7);
        a[kk][mi] = *(const bf16x8*)(Asc + r * 64 + slot * 8);
      }
#pragma unroll
    for (int kk = 0; kk < 2; kk++)
#pragma unroll
      for (int ni = 0; ni < 2; ni++) {
        int r = wc * 64 + ni * 16 + l15;
        int slot = (kk * 4 + g) ^ (r & 7);
        b0[kk][ni] = *(const bf16x8*)(Bsc + r * 64 + slot * 8);
      }
#pragma unroll
    for (int kk = 0; kk < 2; kk++)
#pragma unroll
      for (int ni = 0; ni < 2; ni++) {
        int r = wc * 64 + (ni + 2) * 16 + l15;
        int slot = (kk * 4 + g) ^ (r & 7);
        b1[kk][ni] = *(const bf16x8*)(Bsc + r * 64 + slot * 8);
      }
    __builtin_amdgcn_s_barrier();
    asm volatile("s_waitcnt lgkmcnt(0)" ::: "memory");
    __builtin_amdgcn_sched_barrier(0);
    __builtin_amdgcn_s_setprio(1);
#pragma unroll
    for (int mi = 0; mi < 4; mi++)
#pragma unroll
      for (int ni = 0; ni < 2; ni++)
#pragma unroll
        for (int kk = 0; kk < 2; kk++)
          acc[mi][ni] = __builtin_amdgcn_mfma_f32_16x16x32_bf16(
              a[kk][mi], b0[kk][ni], acc[mi][ni], 0, 0, 0);
    __builtin_amdgcn_s_setprio(0);
    __builtin_amdgcn_s_barrier();

    if (ti + 2 < NT) { stageA(cur, ktn2); stageB(cur, ktn2); }
    __builtin_amdgcn_s_barrier();
    __builtin_amdgcn_s_setprio(1);
#pragma unroll
    for (int mi = 0; mi < 4; mi++)
#pragma unroll
      for (int ni = 0; ni < 2; ni++)
#pragma unroll
        for (int kk = 0; kk < 2; kk++)
          acc[mi][ni + 2] = __builtin_amdgcn_mfma_f32_16x16x32_bf16(
              a[kk][mi], b1[kk][ni], acc[mi][ni + 2], 0, 0, 0);
    __builtin_amdgcn_s_setprio(0);
    if (ti + 2 < NT)      asm volatile("s_waitcnt vmcnt(6)" ::: "memory");
    else if (ti + 1 < NT) asm volatile("s_waitcnt vmcnt(0)" ::: "memory");
    __builtin_amdgcn_s_barrier();
  }

#pragma unroll
  for (int mi = 0; mi < 4; mi++)
#pragma unroll
    for (int ni = 0; ni < 4; ni++) {
      int rowg = m0 + wr * 64 + mi * 16 + g * 4;
      int ncol = nb * 256 + wc * 64 + ni * 16 + l15;
#pragma unroll
      for (int r = 0; r < 4; r++)
        Cf[(size_t)(rowg + r) * 4096 + ncol] = acc[mi][ni][r];
    }
}

// ---------------- RoPE (in place) on K [2048][2048] only ----------------
__global__ __launch_bounds__(256) void rope_k_kernel(
    u16* __restrict__ Kb, const float* __restrict__ freqs,
    const int* __restrict__ start_pos) {
  const int sp = start_pos[0];
  const int total = SEQ * KVW / 2;  // pairs
  for (int idx = blockIdx.x * 256 + threadIdx.x; idx < total;
       idx += gridDim.x * 256) {
    int row = idx >> 10, pi = idx & 1023;
    u16* buf = Kb + (size_t)row * KVW;
    int i = pi & 63;
    float2 cs = *(const float2*)(freqs + (size_t)(sp + row) * 128 + i * 2);
    ushort2 tv = *(ushort2*)(buf + pi * 2);
    float t0 = bf2f(tv.x), t1 = bf2f(tv.y);
    ushort2 o;
    o.x = f2bf(t0 * cs.x - t1 * cs.y);
    o.y = f2bf(t0 * cs.y + t1 * cs.x);
    *(ushort2*)(buf + pi * 2) = o;
  }
}

// ---------------- flash attention + wo-transpose backfill -------------------
__global__ __launch_bounds__(256, 4) void attn_kernel(
    const u16* __restrict__ Q, const u16* __restrict__ Kb,
    const u16* __restrict__ Vt, u16* __restrict__ O,
    const float* __restrict__ freqs, const int* __restrict__ start_pos,
    const float* __restrict__ wo, u16* __restrict__ woT) {
  __shared__ __align__(16) u16 KV[16384];   // K: [0,8192) 64x128, V: [8192,..) 128x64
  __shared__ u16 Ps[4][16 * 72];

  const int t = threadIdx.x;
  const int bid = blockIdx.x;

  if (bid >= 1024) {  // ---- wo transpose tile ----
    u16 (*tile)[68] = (u16(*)[68])KV;
    const int local = bid - 1024;       // 0..4095
    const int n0 = (local & 63) * 64, k0 = (local >> 6) * 64;
#pragma unroll
    for (int i = 0; i < 4; i++) {
      int c = i * 256 + t;
      int r = c >> 4, cq = c & 15;
      float4 v = *(const float4*)(wo + (size_t)(k0 + r) * 4096 + n0 + cq * 4);
      tile[r][cq * 4 + 0] = f2bf(v.x); tile[r][cq * 4 + 1] = f2bf(v.y);
      tile[r][cq * 4 + 2] = f2bf(v.z); tile[r][cq * 4 + 3] = f2bf(v.w);
    }
    __syncthreads();
#pragma unroll
    for (int i = 0; i < 4; i++) {
      int c = i * 256 + t;
      int rn = c >> 4, cq = c & 15;
      ushort4 v;
      v.x = tile[cq * 4 + 0][rn];
      v.y = tile[cq * 4 + 1][rn];
      v.z = tile[cq * 4 + 2][rn];
      v.w = tile[cq * 4 + 3][rn];
      *(ushort4*)(woT + (size_t)(n0 + rn) * KDIM + k0 + cq * 4) = v;
    }
    return;
  }

  const int lane = t & 63;
  const int w = t >> 6;
  const int g = lane >> 4;
  const int l15 = lane & 15;
  const int qb = 31 - (bid >> 5);
  const int h = bid & 31;
  const int hk = h >> 1;

  auto stageK = [&](int kv) {
#pragma unroll
    for (int i = 0; i < 4; i++) {
      int c = i * 256 + t;
      int row = c >> 4, spp = c & 15;
      int col = ((spp ^ (row & 7)) << 3);
      g2l16(Kb + (size_t)(kv * 64 + row) * KVW + hk * HD + col, &KV[c * 8]);
    }
  };
  auto stageV = [&](int kv) {
#pragma unroll
    for (int i = 0; i < 4; i++) {
      int c = i * 256 + t;
      int row = c >> 3, spp = c & 7;
      int col = ((spp ^ (row & 7)) << 3);
      g2l16(Vt + (size_t)(hk * HD + row) * SEQ + kv * 64 + col,
            &KV[8192 + c * 8]);
    }
  };

#pragma unroll
  for (int i = 0; i < 4; i++) {
    int c = i * 256 + t;
    int row = c >> 4, spp = c & 15;
    int col = ((spp ^ (row & 7)) << 3);
    g2l16(Q + (size_t)(qb * 64 + row) * EMBED + h * HD + col, &KV[c * 8]);
  }
  asm volatile("s_waitcnt vmcnt(0)" ::: "memory");
  __builtin_amdgcn_s_barrier();

  // read Q fragments + apply RoPE in-register
  bf16x8 qf[4];
  {
    const int r = w * 16 + l15;
    const int frow = start_pos[0] + qb * 64 + r;
    const float qscale = 0.08838834764831845f;  // 1/sqrt(128)
#pragma unroll
    for (int kk = 0; kk < 4; kk++) {
      int ps = (kk * 4 + g) ^ (r & 7);
      bf16x8 v = *(const bf16x8*)(&KV[r * 128 + ps * 8]);
      bf16x8 o;
      const int d0 = (kk * 4 + g) * 8;   // actual d-octet (swizzle cancels)
#pragma unroll
      for (int p = 0; p < 4; p++) {
        float2 cs = *(const float2*)(freqs + (size_t)frow * 128 + d0 + p * 2);
        float t0 = (float)v[2 * p], t1 = (float)v[2 * p + 1];
        o[2 * p]     = (__bf16)((t0 * cs.x - t1 * cs.y) * qscale);
        o[2 * p + 1] = (__bf16)((t0 * cs.y + t1 * cs.x) * qscale);
      }
      qf[kk] = o;
    }
  }
  asm volatile("s_waitcnt lgkmcnt(0)" ::: "memory");
  __builtin_amdgcn_s_barrier();

  f32x4 oacc[8];
#pragma unroll
  for (int i = 0; i < 8; i++) oacc[i] = (f32x4){0.f, 0.f, 0.f, 0.f};
  float mrow = -1e30f, lrow = 0.f;
  const int qg = qb * 64 + w * 16 + l15;

  for (int kv = 0; kv <= qb; kv++) {
    stageK(kv); stageV(kv);
    asm volatile("s_waitcnt vmcnt(0)" ::: "memory");
    __builtin_amdgcn_s_barrier();

    f32x4 sfragT[4];
    __builtin_amdgcn_s_setprio(1);
#pragma unroll
    for (int ni = 0; ni < 4; ni++) {
      f32x4 s = (f32x4){0.f, 0.f, 0.f, 0.f};
      int r = ni * 16 + l15;
#pragma unroll
      for (int kk = 0; kk < 4; kk++) {
        int ps = (kk * 4 + g) ^ (r & 7);
        bf16x8 a = *(const bf16x8*)(&KV[r * 128 + ps * 8]);
        s = __builtin_amdgcn_mfma_f32_16x16x32_bf16(a, qf[kk], s, 0, 0, 0);
      }
      sfragT[ni] = s;
    }
    __builtin_amdgcn_s_setprio(0);

    if (kv == qb) {
#pragma unroll
      for (int ni = 0; ni < 4; ni++) {
        int colg = kv * 64 + ni * 16 + g * 4;
#pragma unroll
        for (int r = 0; r < 4; r++)
          if (colg + r > qg) sfragT[ni][r] = -1e30f;
      }
    }

    float m16 = sfragT[0][0];
#pragma unroll
    for (int ni = 0; ni < 4; ni++)
#pragma unroll
      for (int r = 0; r < 4; r++) m16 = fmaxf(m16, sfragT[ni][r]);
    m16 = fmaxf(m16, __shfl_xor(m16, 16));
    m16 = fmaxf(m16, __shfl_xor(m16, 32));
    float mnew = fmaxf(mrow, m16);
    float sc = __expf(mrow - mnew);
    mrow = mnew;

    float rsum = 0.f;
#pragma unroll
    for (int ni = 0; ni < 4; ni++) {
#pragma unroll
      for (int r = 0; r < 4; r++) {
        float p = __expf(sfragT[ni][r] - mrow);
        rsum += p;
        Ps[w][l15 * 72 + ni * 16 + g * 4 + r] = f2bf(p);
      }
    }
    rsum += __shfl_xor(rsum, 16);
    rsum += __shfl_xor(rsum, 32);
    lrow = lrow * sc + rsum;

    float scr[4];
#pragma unroll
    for (int r = 0; r < 4; r++) scr[r] = __shfl(sc, g * 4 + r, 64);
#pragma unroll
    for (int nf = 0; nf < 8; nf++)
#pragma unroll
      for (int r = 0; r < 4; r++) oacc[nf][r] *= scr[r];

    asm volatile("s_waitcnt lgkmcnt(0)" ::: "memory");

    bf16x8 pa[2];
#pragma unroll
    for (int kk = 0; kk < 2; kk++)
      pa[kk] = *(const bf16x8*)(&Ps[w][l15 * 72 + kk * 32 + g * 8]);
    __builtin_amdgcn_s_setprio(1);
#pragma unroll
    for (int nf = 0; nf < 8; nf++) {
      int r = nf * 16 + l15;
#pragma unroll
      for (int kk = 0; kk < 2; kk++) {
        int ps = (kk * 4 + g) ^ (r & 7);
        bf16x8 b = *(const bf16x8*)(&KV[8192 + r * 64 + ps * 8]);
        oacc[nf] = __builtin_amdgcn_mfma_f32_16x16x32_bf16(pa[kk], b, oacc[nf], 0, 0, 0);
      }
    }
    __builtin_amdgcn_s_setprio(0);
    __builtin_amdgcn_s_barrier();
  }

  float lr[4];
#pragma unroll
  for (int r = 0; r < 4; r++) lr[r] = __shfl(lrow, g * 4 + r, 64);
#pragma unroll
  for (int nf = 0; nf < 8; nf++) {
#pragma unroll
    for (int r = 0; r < 4; r++) {
      int rowg = qb * 64 + w * 16 + g * 4 + r;
      float v = oacc[nf][r] / lr[r];
      O[(size_t)rowg * EMBED + h * HD + nf * 16 + l15] = f2bf(v);
    }
  }
}

extern "C" void kernel_launch(void* const* d_in, const int* in_sizes, int n_in,
                              void* d_out, int out_size, void* d_ws, size_t ws_size,
                              hipStream_t stream) {
  const float* x  = (const float*)d_in[0];
  const float* fc = (const float*)d_in[1];
  const float* wq = (const float*)d_in[2];
  const float* wk = (const float*)d_in[3];
  const float* wv = (const float*)d_in[4];
  const float* wo = (const float*)d_in[5];
  const int* sp = (const int*)d_in[6];

  char* ws = (char*)d_ws;
  u16* wqT = (u16*)(ws);                      // bf16 [4096][4096]
  u16* wkT = (u16*)(ws + 33554432ull);        // bf16 [2048][4096]
  u16* wvT = (u16*)(ws + 50331648ull);        // bf16 [2048][4096]
  u16* woT = (u16*)(ws + 67108864ull);        // bf16 [4096][4096]
  u16* xb  = (u16*)(ws + 100663296ull);       // bf16 [2048][4096]
  u16* Qb  = (u16*)(ws + 117440512ull);       // bf16 [2048][4096] (raw, no rope)
  u16* Kb  = (u16*)(ws + 134217728ull);       // bf16 [2048][2048]
  u16* Vt  = (u16*)(ws + 142606336ull);       // bf16 [2048][2048]
  u16* Ob  = (u16*)(ws + 150994944ull);       // bf16 [2048][4096]

  prep_kernel<<<dim3(10240), 256, 0, stream>>>(x, xb, wq, wqT, wk, wkT,
                                               wv, wvT);
  gemm8_qkv<<<dim3(256), 512, 0, stream>>>(xb, wqT, wkT, wvT, Qb, Kb, Vt);
  rope_k_kernel<<<dim3(1024), 256, 0, stream>>>(Kb, fc, sp);
  attn_kernel<<<dim3(5120), 256, 0, stream>>>(Qb, Kb, Vt, Ob, fc, sp,
                                              wo, woT);
  gemm8_op<<<dim3(256), 512, 0, stream>>>(Ob, woT, (float*)d_out);
}